// Round 16
// baseline (909.577 us; speedup 1.0000x reference)
//
#include <hip/hip_runtime.h>
#include <hip/hip_bf16.h>

// 3-layer stacked LSTM forward (eval). Round 16 = r13 (837us best) with the
// scans' h-broadcast moved OFF the DS pipe:
//  r13 limiter: 8 waves x 16 ds_read_b128 = 128 DS-insts/CU/step (~1536cyc).
//  r16: h distributed 1 bf16-pair/lane via ONE ds_read_b32 per wave per step;
//  broadcast via v_readlane -> SGPR; dot2 takes the SGPR as src1 (VOP3P allows
//  1 SGPR read). DS insts/step: 128 -> 8. Accumulation order unchanged
//  (pairs 0..63 sequential) -> bit-identical absmax.
//  Topology r13-identical: scan1 512thr/1row-per-thread, w=16 uint4 (64 VGPR,
//  waves_per_eu(2,2) + in-loop pin); scan2 256thr, w=8 uint4, (1,1).
//  gemm_mfma / gemm_xg3b / scan3 / cvt: byte-identical to r13.
// T=512, B=256, IN=97(pad128), H1=128, H2=64, H3=1.

#define T_TOT 512
#define BB    256
#define CH    128
#define NCH   4

typedef __attribute__((ext_vector_type(8))) short  short8v;   // 8 bf16
typedef __attribute__((ext_vector_type(4))) float  float4v;   // MFMA acc

// acc += w.lo*h.lo + w.hi*h.hi, h pair in an SGPR (VOP3P, 1 SGPR src allowed)
#define DOT2BS(acc, wu, hs) \
    asm("v_dot2_f32_bf16 %0, %1, %2, %0" : "+v"(acc) : "v"(wu), "s"(hs))

__device__ __forceinline__ float sigm(float x) {
    float e = __expf(-x);
    return __builtin_amdgcn_rcpf(1.0f + e);
}
__device__ __forceinline__ float tanh_(float x) {
    float e = __expf(2.0f * x);
    return 1.0f - 2.0f * __builtin_amdgcn_rcpf(1.0f + e);
}
__device__ __forceinline__ unsigned short f2bf(float x) {
    __hip_bfloat16 b = __float2bfloat16(x);
    return __builtin_bit_cast(unsigned short, b);
}
__device__ __forceinline__ float b2f(unsigned short u) {
    unsigned int x = (unsigned int)u << 16;
    return __builtin_bit_cast(float, x);
}

// ---------------------------------------------------------------------------
__global__ __launch_bounds__(256) void cvt_pad(
    const float* __restrict__ in, __hip_bfloat16* __restrict__ out, int R, int K)
{
    int total = R * 128;
    for (int idx = blockIdx.x * 256 + threadIdx.x; idx < total; idx += gridDim.x * 256) {
        int r = idx >> 7, c = idx & 127;
        float v = (c < K) ? in[(size_t)r * K + c] : 0.0f;
        out[idx] = __float2bfloat16(v);
    }
}
__global__ __launch_bounds__(256) void cvt_plain(
    const float* __restrict__ in, __hip_bfloat16* __restrict__ out, int n)
{
    int i = blockIdx.x * 256 + threadIdx.x;
    if (i < n) out[i] = __float2bfloat16(in[i]);
}
__global__ __launch_bounds__(256) void addvec(
    const float* __restrict__ a, const float* __restrict__ b, float* __restrict__ o, int n)
{
    int i = blockIdx.x * 256 + threadIdx.x;
    if (i < n) o[i] = a[i] + b[i];
}

// ---------------------------------------------------------------------------
// bf16 MFMA GEMM (r4, verified): C[M,N] = A[M,128] * W[N,128]^T + bias
// ---------------------------------------------------------------------------
__global__ __launch_bounds__(256) void gemm_mfma(
    const __hip_bfloat16* __restrict__ A,
    const __hip_bfloat16* __restrict__ W,
    const float* __restrict__ bias,
    float* __restrict__ C, int N)
{
    __shared__ __hip_bfloat16 At[128 * 128];   // 32 KB

    const int tid  = threadIdx.x;
    const int lane = tid & 63;
    const int wid  = tid >> 6;
    const int m0   = blockIdx.x * 128;
    const int n0   = blockIdx.y * 128;
    const int wr   = wid >> 1;
    const int wc   = wid & 1;

    short8v bfrag[4][4];  // [nf][kf]
    {
        const char* Wg = (const char*)W;
#pragma unroll
        for (int nf = 0; nf < 4; ++nf) {
            int row = n0 + wc * 64 + nf * 16 + (lane & 15);
#pragma unroll
            for (int kf = 0; kf < 4; ++kf) {
                int colb = (kf * 32 + (lane >> 4) * 8) * 2;
                bfrag[nf][kf] = *(const short8v*)(Wg + (size_t)row * 256 + colb);
            }
        }
    }
    {
        const char* Ag = (const char*)(A + (size_t)m0 * 128);
        char* As = (char*)At;
#pragma unroll
        for (int r2 = 0; r2 < 8; ++r2) {
            int off = r2 * 4096 + tid * 16;
            int row = off >> 8;
            int bir = off & 255;
            short8v v = *(const short8v*)(Ag + (size_t)row * 256 + bir);
            int sw = bir ^ ((row & 7) << 4);
            *(short8v*)(As + row * 256 + sw) = v;
        }
    }
    __syncthreads();

    float4v acc[4][4] = {};
#pragma unroll
    for (int kf = 0; kf < 4; ++kf) {
        short8v af[4];
#pragma unroll
        for (int mf = 0; mf < 4; ++mf) {
            int row   = wr * 64 + mf * 16 + (lane & 15);
            int kbyte = kf * 64 + (lane >> 4) * 16;
            int sw    = kbyte ^ ((row & 7) << 4);
            af[mf] = *(const short8v*)((const char*)At + row * 256 + sw);
        }
#pragma unroll
        for (int mf = 0; mf < 4; ++mf)
#pragma unroll
            for (int nf = 0; nf < 4; ++nf)
                acc[mf][nf] = __builtin_amdgcn_mfma_f32_16x16x32_bf16(
                    af[mf], bfrag[nf][kf], acc[mf][nf], 0, 0, 0);
    }

#pragma unroll
    for (int nf = 0; nf < 4; ++nf) {
        int col = n0 + wc * 64 + nf * 16 + (lane & 15);
        float bv = bias[col];
#pragma unroll
        for (int mf = 0; mf < 4; ++mf) {
            int rbase = m0 + wr * 64 + mf * 16 + (lane >> 4) * 4;
#pragma unroll
            for (int r = 0; r < 4; ++r)
                C[(size_t)(rbase + r) * N + col] = acc[mf][nf][r] + bv;
        }
    }
}

// ---------------------------------------------------------------------------
// scan1 (H=128): 256 blocks x 512 thr (8 waves), thread n owns gate-row n
// (r13 topology). NEW: h-broadcast via 1 ds_read_b32/wave (lane l holds pair
// l) + v_readlane -> SGPR feeding dot2 src1. 8 DS-insts/CU/step vs r13's 128.
// ---------------------------------------------------------------------------
__global__ __launch_bounds__(512)
__attribute__((amdgpu_waves_per_eu(2, 2)))
void lstm_scan1(
    const float* __restrict__ xg,        // [Tc, BB, 512] f32, bias included
    const unsigned int* __restrict__ Wp, // [512 rows][64 uint] bf16-pairs
    __hip_bfloat16* __restrict__ hout,   // [Tc, BB, 128]
    float* __restrict__ hstate, float* __restrict__ cstate,
    int Tc, int first)
{
    const int n    = threadIdx.x;     // gate-row 0..511
    const int lane = n & 63;
    const int row  = blockIdx.x;
    __shared__ unsigned int hbuf[2][64];   // 128 bf16 as 64 pairs, dbuf
    __shared__ float g_lds[512];

    uint4 w[16];   // 64 VGPR of weights, static-indexed
    {
        const uint4* wr_ = (const uint4*)(Wp + (size_t)n * 64);
#pragma unroll
        for (int j = 0; j < 16; ++j) w[j] = wr_[j];
    }

    float c = 0.0f, hf = 0.0f;
    if (n < 128) {
        c  = first ? 0.0f : cstate[row * 128 + n];
        hf = first ? 0.0f : hstate[row * 128 + n];
        ((unsigned short*)hbuf[0])[n] = f2bf(hf);
    }
    __syncthreads();

    const float* px = xg + (size_t)row * 512 + n;
    float xc = px[0];
    float xn = (Tc > 1) ? px[(size_t)BB * 512] : 0.0f;

    int cur = 0;
    for (int t = 0; t < Tc; ++t) {
        // In-loop pin (r13-verified): weights loop-carried, un-reloadable.
#pragma unroll
        for (int j = 0; j < 16; ++j)
            asm volatile("" : "+v"(w[j].x), "+v"(w[j].y), "+v"(w[j].z), "+v"(w[j].w));

        float a = xc;
        xc = xn;
        if (t + 2 < Tc) xn = px[(size_t)(t + 2) * BB * 512];

        // ONE ds_read_b32 per wave: lane l holds h-pair l (2 bf16).
        unsigned int hv = hbuf[cur][lane];

#pragma unroll
        for (int j = 0; j < 16; ++j) {
            unsigned int h0 = __builtin_amdgcn_readlane(hv, 4 * j + 0);
            DOT2BS(a, w[j].x, h0);
            unsigned int h1 = __builtin_amdgcn_readlane(hv, 4 * j + 1);
            DOT2BS(a, w[j].y, h1);
            unsigned int h2 = __builtin_amdgcn_readlane(hv, 4 * j + 2);
            DOT2BS(a, w[j].z, h2);
            unsigned int h3 = __builtin_amdgcn_readlane(hv, 4 * j + 3);
            DOT2BS(a, w[j].w, h3);
        }
        g_lds[n] = a;
        __syncthreads();

        if (n < 128) {
            float i_ = sigm(g_lds[n]);
            float f_ = sigm(g_lds[n + 128]);
            float g_ = tanh_(g_lds[n + 256]);
            float o_ = sigm(g_lds[n + 384]);
            c  = fmaf(f_, c, i_ * g_);
            hf = o_ * tanh_(c);
            unsigned short hb16 = f2bf(hf);
            ((unsigned short*)hbuf[cur ^ 1])[n] = hb16;
            ((unsigned short*)hout)[((size_t)t * BB + row) * 128 + n] = hb16;
        }
        cur ^= 1;
        __syncthreads();
    }
    if (n < 128) {
        cstate[row * 128 + n] = c;
        hstate[row * 128 + n] = hf;
    }
}

// ---------------------------------------------------------------------------
// scan2 (H=64): 256 blocks x 256 thr (4 waves), thread n owns gate-row n.
// Same readlane-broadcast scheme: 32 pairs, lanes >=32 read pair (lane&31).
// ---------------------------------------------------------------------------
__global__ __launch_bounds__(256)
__attribute__((amdgpu_waves_per_eu(1, 1)))
void lstm_scan2(
    const float* __restrict__ xg,        // [Tc, BB, 256]
    const unsigned int* __restrict__ Wp, // [256 rows][32 uint] bf16-pairs
    __hip_bfloat16* __restrict__ hout,   // [Tc, BB, 64] bf16
    float* __restrict__ hstate, float* __restrict__ cstate,
    int Tc, int first)
{
    const int n    = threadIdx.x;   // gate-row 0..255
    const int lane = n & 63;
    const int row  = blockIdx.x;
    __shared__ unsigned int hbuf[2][32];
    __shared__ float g_lds[256];

    uint4 w[8];
    {
        const uint4* wr_ = (const uint4*)(Wp + (size_t)n * 32);
#pragma unroll
        for (int j = 0; j < 8; ++j) w[j] = wr_[j];
    }

    float c = 0.0f, hf = 0.0f;
    if (n < 64) {
        c  = first ? 0.0f : cstate[row * 64 + n];
        hf = first ? 0.0f : hstate[row * 64 + n];
        ((unsigned short*)hbuf[0])[n] = f2bf(hf);
    }
    __syncthreads();

    const float* px = xg + (size_t)row * 256 + n;
    float xc = px[0];
    float xn = (Tc > 1) ? px[(size_t)BB * 256] : 0.0f;

    int cur = 0;
    for (int t = 0; t < Tc; ++t) {
#pragma unroll
        for (int j = 0; j < 8; ++j)
            asm volatile("" : "+v"(w[j].x), "+v"(w[j].y), "+v"(w[j].z), "+v"(w[j].w));

        float a = xc;
        xc = xn;
        if (t + 2 < Tc) xn = px[(size_t)(t + 2) * BB * 256];

        unsigned int hv = hbuf[cur][lane & 31];   // 1 ds_read_b32 per wave

#pragma unroll
        for (int j = 0; j < 8; ++j) {
            unsigned int h0 = __builtin_amdgcn_readlane(hv, 4 * j + 0);
            DOT2BS(a, w[j].x, h0);
            unsigned int h1 = __builtin_amdgcn_readlane(hv, 4 * j + 1);
            DOT2BS(a, w[j].y, h1);
            unsigned int h2 = __builtin_amdgcn_readlane(hv, 4 * j + 2);
            DOT2BS(a, w[j].z, h2);
            unsigned int h3 = __builtin_amdgcn_readlane(hv, 4 * j + 3);
            DOT2BS(a, w[j].w, h3);
        }
        g_lds[n] = a;
        __syncthreads();

        if (n < 64) {
            float i_ = sigm(g_lds[n]);
            float f_ = sigm(g_lds[n + 64]);
            float g_ = tanh_(g_lds[n + 128]);
            float o_ = sigm(g_lds[n + 192]);
            c  = fmaf(f_, c, i_ * g_);
            hf = o_ * tanh_(c);
            unsigned short hb16 = f2bf(hf);
            ((unsigned short*)hbuf[cur ^ 1])[n] = hb16;
            ((unsigned short*)hout)[((size_t)t * BB + row) * 64 + n] = hb16;
        }
        cur ^= 1;
        __syncthreads();
    }
    if (n < 64) {
        cstate[row * 64 + n] = c;
        hstate[row * 64 + n] = hf;
    }
}

// ---------------------------------------------------------------------------
// Layer-3 input GEMM, bf16 X (r13): out[m,0..3] = sum_k X[m,k]*W[n,k] + b
// ---------------------------------------------------------------------------
__global__ __launch_bounds__(256) void gemm_xg3b(
    const __hip_bfloat16* __restrict__ X,  // [M, 64] bf16
    const float* __restrict__ W,           // [4, 64] f32
    const float* __restrict__ b1, const float* __restrict__ b2,
    float* __restrict__ out)               // [M, 4]
{
    __shared__ __align__(16) float ws4[4][64];
    __shared__ float bb[4];
    const int tid = threadIdx.x;
    {
        const int nn = tid >> 6, kk = tid & 63;
        ws4[nn][kk] = W[nn * 64 + kk];
    }
    if (tid < 4) bb[tid] = b1[tid] + b2[tid];
    __syncthreads();

    const int m = blockIdx.x * 256 + tid;
    const uint4* xr = reinterpret_cast<const uint4*>(X + (size_t)m * 64);
    float a0 = bb[0], a1 = bb[1], a2 = bb[2], a3 = bb[3];
#pragma unroll
    for (int kk = 0; kk < 8; ++kk) {       // 8 bf16 per uint4
        uint4 v = xr[kk];
        float xf[8];
        xf[0] = b2f((unsigned short)(v.x & 0xffff));
        xf[1] = b2f((unsigned short)(v.x >> 16));
        xf[2] = b2f((unsigned short)(v.y & 0xffff));
        xf[3] = b2f((unsigned short)(v.y >> 16));
        xf[4] = b2f((unsigned short)(v.z & 0xffff));
        xf[5] = b2f((unsigned short)(v.z >> 16));
        xf[6] = b2f((unsigned short)(v.w & 0xffff));
        xf[7] = b2f((unsigned short)(v.w >> 16));
#pragma unroll
        for (int j = 0; j < 8; ++j) {
            int k = kk * 8 + j;
            a0 = fmaf(xf[j], ws4[0][k], a0);
            a1 = fmaf(xf[j], ws4[1][k], a1);
            a2 = fmaf(xf[j], ws4[2][k], a2);
            a3 = fmaf(xf[j], ws4[3][k], a3);
        }
    }
    float4 o; o.x = a0; o.y = a1; o.z = a2; o.w = a3;
    *reinterpret_cast<float4*>(&out[(size_t)m * 4]) = o;
}

// ---------------------------------------------------------------------------
// Layer-3 scan: 8-deep static prefetch ring (r5, verified).
// ---------------------------------------------------------------------------
__global__ __launch_bounds__(256) void lstm_scan3(
    const float* __restrict__ xg,   // [T, B, 4]
    const float* __restrict__ Whh,  // [4, 1]
    float* __restrict__ out,        // [T, B]
    int T)
{
    const int b = threadIdx.x;
    const float w0 = Whh[0], w1 = Whh[1], w2 = Whh[2], w3 = Whh[3];
    float h = 0.0f, c = 0.0f;
    const float4* p = reinterpret_cast<const float4*>(xg) + b;

    float4 cur[8], nxt[8];
#pragma unroll
    for (int j = 0; j < 8; ++j) cur[j] = p[(size_t)j * BB];

    for (int t0 = 0; t0 < T; t0 += 8) {
#pragma unroll
        for (int j = 0; j < 8; ++j) {
            int tt = t0 + 8 + j;
            if (tt < T) nxt[j] = p[(size_t)tt * BB];
        }
#pragma unroll
        for (int j = 0; j < 8; ++j) {
            float4 g4 = cur[j];
            float gi = fmaf(h, w0, g4.x);
            float gf = fmaf(h, w1, g4.y);
            float gg = fmaf(h, w2, g4.z);
            float go = fmaf(h, w3, g4.w);
            float i_ = sigm(gi);
            float f_ = sigm(gf);
            float g_ = tanh_(gg);
            float o_ = sigm(go);
            c = fmaf(f_, c, i_ * g_);
            h = o_ * tanh_(c);
            out[(size_t)(t0 + j) * BB + b] = h;
        }
#pragma unroll
        for (int j = 0; j < 8; ++j) cur[j] = nxt[j];
    }
}

// ---------------------------------------------------------------------------
extern "C" void kernel_launch(void* const* d_in, const int* in_sizes, int n_in,
                              void* d_out, int out_size, void* d_ws, size_t ws_size,
                              hipStream_t stream) {
    const float* x    = (const float*)d_in[0];
    const float* Wih1 = (const float*)d_in[1];
    const float* Whh1 = (const float*)d_in[2];
    const float* bih1 = (const float*)d_in[3];
    const float* bhh1 = (const float*)d_in[4];
    const float* Wih2 = (const float*)d_in[5];
    const float* Whh2 = (const float*)d_in[6];
    const float* bih2 = (const float*)d_in[7];
    const float* bhh2 = (const float*)d_in[8];
    const float* Wih3 = (const float*)d_in[9];
    const float* Whh3 = (const float*)d_in[10];
    const float* bih3 = (const float*)d_in[11];
    const float* bhh3 = (const float*)d_in[12];
    float* out = (float*)d_out;

    char* ws = (char*)d_ws;
    // Workspace layout, ~187.4 MB total:
    float*          xg1c  = (float*)(ws + 0);                   // [CH,B,512] f32 = 67,108,864
    float*          xg2c  = (float*)(ws + 67108864);            // [CH,B,256] f32 = 33,554,432
    __hip_bfloat16* xb    = (__hip_bfloat16*)(ws + 100663296);  // [T,B,128] bf16 = 33,554,432
    __hip_bfloat16* h1b   = (__hip_bfloat16*)(ws + 134217728);  // [T,B,128] bf16 = 33,554,432
    __hip_bfloat16* h2bb  = (__hip_bfloat16*)(ws + 167772160);  // [T,B,64]  bf16 = 16,777,216
    float*          xg3   = (float*)(ws + 184549376);           // [T,B,4]   f32  =  2,097,152
    __hip_bfloat16* wb1   = (__hip_bfloat16*)(ws + 186646528);  // [512,128] =   131,072
    __hip_bfloat16* whb1  = (__hip_bfloat16*)(ws + 186777600);  // [512,128] =   131,072
    __hip_bfloat16* wb2   = (__hip_bfloat16*)(ws + 186908672);  // [256,128] =    65,536
    __hip_bfloat16* whb2  = (__hip_bfloat16*)(ws + 186974208);  // [256,64]  =    32,768
    float*          bias1 = (float*)(ws + 187006976);           //     2,048
    float*          bias2 = (float*)(ws + 187009024);           //     1,024
    float*          bias3 = (float*)(ws + 187010048);           //        64
    float*          st1h  = (float*)(ws + 187010112);           // [B,128] f32
    float*          st1c  = (float*)(ws + 187141184);
    float*          st2h  = (float*)(ws + 187272256);           // [B,64] f32
    float*          st2c  = (float*)(ws + 187337792);

    // ---- P0: conversions / bias prep ----
    cvt_pad<<<4096, 256, 0, stream>>>(x, xb, T_TOT * BB, 97);
    cvt_pad<<<256, 256, 0, stream>>>(Wih1, wb1, 512, 97);
    cvt_plain<<<256, 256, 0, stream>>>(Whh1, whb1, 512 * 128);
    cvt_plain<<<128, 256, 0, stream>>>(Wih2, wb2, 256 * 128);
    cvt_plain<<<64, 256, 0, stream>>>(Whh2, whb2, 256 * 64);
    addvec<<<2, 256, 0, stream>>>(bih1, bhh1, bias1, 512);
    addvec<<<1, 256, 0, stream>>>(bih2, bhh2, bias2, 256);

    // ---- Layer 1 (chunked over T) ----
    for (int c0 = 0; c0 < NCH; ++c0) {
        gemm_mfma<<<dim3(CH * BB / 128, 512 / 128), 256, 0, stream>>>(
            xb + (size_t)c0 * CH * BB * 128, wb1, bias1, xg1c, 512);
        lstm_scan1<<<BB, 512, 0, stream>>>(
            xg1c, (const unsigned int*)whb1,
            h1b + (size_t)c0 * CH * BB * 128, st1h, st1c, CH, c0 == 0);
    }
    // ---- Layer 2 (chunked over T) ----
    for (int c0 = 0; c0 < NCH; ++c0) {
        gemm_mfma<<<dim3(CH * BB / 128, 256 / 128), 256, 0, stream>>>(
            h1b + (size_t)c0 * CH * BB * 128, wb2, bias2, xg2c, 256);
        lstm_scan2<<<BB, 256, 0, stream>>>(
            xg2c, (const unsigned int*)whb2,
            h2bb + (size_t)c0 * CH * BB * 64, st2h, st2c, CH, c0 == 0);
    }
    // ---- Layer 3 ----
    gemm_xg3b<<<T_TOT * BB / 256, 256, 0, stream>>>(h2bb, Wih3, bih3, bhh3, xg3);
    lstm_scan3<<<1, 256, 0, stream>>>(xg3, Whh3, out, T_TOT);
}

// Round 17
// 891.954 us; speedup vs baseline: 1.0198x; 1.0198x over previous
//
#include <hip/hip_runtime.h>
#include <hip/hip_bf16.h>

// 3-layer stacked LSTM forward (eval). Round 17 = r13 (837us best) with the
// scans' h-broadcast HYBRID-split between the DS pipe and VALU:
//  r13: 16 ds_read_b128/wave -> DS-bound (128 insts/CU/step ~1536cyc, meas 1762)
//  r16: 64 readlane/wave     -> VALU-bound (VALUBusy 55%, meas 2062)
//  r17: pairs 0..39 via readlane (40 VALU), pairs 40..63 via 6 ds_read_b128.
//       DS/CU ~576cyc, VALU/SIMD ~536cyc -- balanced. Accumulation order
//       (pairs ascending) unchanged -> bit-identical absmax (0.001953125).
//  scan2 same split: 20 readlane + 3 b128 (balance ~144/144).
//  Topology/residency identical to r13: scan1 512thr/1row-per-thread, 16 uint4
//  weights (64 VGPR, waves_per_eu(2,2) + in-loop pin, r13-verified resident);
//  scan2 256thr, 8 uint4, (1,1). gemm_mfma/gemm_xg3b/scan3/cvt: unchanged.
// T=512, B=256, IN=97(pad128), H1=128, H2=64, H3=1.

#define T_TOT 512
#define BB    256
#define CH    128
#define NCH   4

typedef __attribute__((ext_vector_type(8))) short  short8v;   // 8 bf16
typedef __attribute__((ext_vector_type(4))) float  float4v;   // MFMA acc

// acc += w.lo*h.lo + w.hi*h.hi, h pair in a VGPR (VOP3P, verified r5/r6)
#define DOT2BF(acc, wu, hu) \
    asm("v_dot2_f32_bf16 %0, %1, %2, %0" : "+v"(acc) : "v"(wu), "v"(hu))
// acc += w.lo*h.lo + w.hi*h.hi, h pair in an SGPR (1 SGPR src ok; verified r16)
#define DOT2BS(acc, wu, hs) \
    asm("v_dot2_f32_bf16 %0, %1, %2, %0" : "+v"(acc) : "v"(wu), "s"(hs))

__device__ __forceinline__ float sigm(float x) {
    float e = __expf(-x);
    return __builtin_amdgcn_rcpf(1.0f + e);
}
__device__ __forceinline__ float tanh_(float x) {
    float e = __expf(2.0f * x);
    return 1.0f - 2.0f * __builtin_amdgcn_rcpf(1.0f + e);
}
__device__ __forceinline__ unsigned short f2bf(float x) {
    __hip_bfloat16 b = __float2bfloat16(x);
    return __builtin_bit_cast(unsigned short, b);
}
__device__ __forceinline__ float b2f(unsigned short u) {
    unsigned int x = (unsigned int)u << 16;
    return __builtin_bit_cast(float, x);
}

// ---------------------------------------------------------------------------
__global__ __launch_bounds__(256) void cvt_pad(
    const float* __restrict__ in, __hip_bfloat16* __restrict__ out, int R, int K)
{
    int total = R * 128;
    for (int idx = blockIdx.x * 256 + threadIdx.x; idx < total; idx += gridDim.x * 256) {
        int r = idx >> 7, c = idx & 127;
        float v = (c < K) ? in[(size_t)r * K + c] : 0.0f;
        out[idx] = __float2bfloat16(v);
    }
}
__global__ __launch_bounds__(256) void cvt_plain(
    const float* __restrict__ in, __hip_bfloat16* __restrict__ out, int n)
{
    int i = blockIdx.x * 256 + threadIdx.x;
    if (i < n) out[i] = __float2bfloat16(in[i]);
}
__global__ __launch_bounds__(256) void addvec(
    const float* __restrict__ a, const float* __restrict__ b, float* __restrict__ o, int n)
{
    int i = blockIdx.x * 256 + threadIdx.x;
    if (i < n) o[i] = a[i] + b[i];
}

// ---------------------------------------------------------------------------
// bf16 MFMA GEMM (r4, verified): C[M,N] = A[M,128] * W[N,128]^T + bias
// ---------------------------------------------------------------------------
__global__ __launch_bounds__(256) void gemm_mfma(
    const __hip_bfloat16* __restrict__ A,
    const __hip_bfloat16* __restrict__ W,
    const float* __restrict__ bias,
    float* __restrict__ C, int N)
{
    __shared__ __hip_bfloat16 At[128 * 128];   // 32 KB

    const int tid  = threadIdx.x;
    const int lane = tid & 63;
    const int wid  = tid >> 6;
    const int m0   = blockIdx.x * 128;
    const int n0   = blockIdx.y * 128;
    const int wr   = wid >> 1;
    const int wc   = wid & 1;

    short8v bfrag[4][4];  // [nf][kf]
    {
        const char* Wg = (const char*)W;
#pragma unroll
        for (int nf = 0; nf < 4; ++nf) {
            int row = n0 + wc * 64 + nf * 16 + (lane & 15);
#pragma unroll
            for (int kf = 0; kf < 4; ++kf) {
                int colb = (kf * 32 + (lane >> 4) * 8) * 2;
                bfrag[nf][kf] = *(const short8v*)(Wg + (size_t)row * 256 + colb);
            }
        }
    }
    {
        const char* Ag = (const char*)(A + (size_t)m0 * 128);
        char* As = (char*)At;
#pragma unroll
        for (int r2 = 0; r2 < 8; ++r2) {
            int off = r2 * 4096 + tid * 16;
            int row = off >> 8;
            int bir = off & 255;
            short8v v = *(const short8v*)(Ag + (size_t)row * 256 + bir);
            int sw = bir ^ ((row & 7) << 4);
            *(short8v*)(As + row * 256 + sw) = v;
        }
    }
    __syncthreads();

    float4v acc[4][4] = {};
#pragma unroll
    for (int kf = 0; kf < 4; ++kf) {
        short8v af[4];
#pragma unroll
        for (int mf = 0; mf < 4; ++mf) {
            int row   = wr * 64 + mf * 16 + (lane & 15);
            int kbyte = kf * 64 + (lane >> 4) * 16;
            int sw    = kbyte ^ ((row & 7) << 4);
            af[mf] = *(const short8v*)((const char*)At + row * 256 + sw);
        }
#pragma unroll
        for (int mf = 0; mf < 4; ++mf)
#pragma unroll
            for (int nf = 0; nf < 4; ++nf)
                acc[mf][nf] = __builtin_amdgcn_mfma_f32_16x16x32_bf16(
                    af[mf], bfrag[nf][kf], acc[mf][nf], 0, 0, 0);
    }

#pragma unroll
    for (int nf = 0; nf < 4; ++nf) {
        int col = n0 + wc * 64 + nf * 16 + (lane & 15);
        float bv = bias[col];
#pragma unroll
        for (int mf = 0; mf < 4; ++mf) {
            int rbase = m0 + wr * 64 + mf * 16 + (lane >> 4) * 4;
#pragma unroll
            for (int r = 0; r < 4; ++r)
                C[(size_t)(rbase + r) * N + col] = acc[mf][nf][r] + bv;
        }
    }
}

// ---------------------------------------------------------------------------
// scan1 (H=128): 256 blocks x 512 thr (8 waves), thread n owns gate-row n.
// HYBRID h-broadcast: pairs 0..39 via v_readlane->SGPR dot2 (hv = 1 ds_read_b32
// per wave), pairs 40..63 via 6 ds_read_b128. DS ~576cyc/CU, VALU ~536cyc/SIMD.
// ---------------------------------------------------------------------------
__global__ __launch_bounds__(512)
__attribute__((amdgpu_waves_per_eu(2, 2)))
void lstm_scan1(
    const float* __restrict__ xg,        // [Tc, BB, 512] f32, bias included
    const unsigned int* __restrict__ Wp, // [512 rows][64 uint] bf16-pairs
    __hip_bfloat16* __restrict__ hout,   // [Tc, BB, 128]
    float* __restrict__ hstate, float* __restrict__ cstate,
    int Tc, int first)
{
    const int n    = threadIdx.x;     // gate-row 0..511
    const int lane = n & 63;
    const int row  = blockIdx.x;
    __shared__ unsigned int hbuf[2][64];   // 128 bf16 as 64 pairs, dbuf
    __shared__ float g_lds[512];

    uint4 w[16];   // 64 VGPR of weights, static-indexed (resident: r13 VGPR=88)
    {
        const uint4* wr_ = (const uint4*)(Wp + (size_t)n * 64);
#pragma unroll
        for (int j = 0; j < 16; ++j) w[j] = wr_[j];
    }

    float c = 0.0f, hf = 0.0f;
    if (n < 128) {
        c  = first ? 0.0f : cstate[row * 128 + n];
        hf = first ? 0.0f : hstate[row * 128 + n];
        ((unsigned short*)hbuf[0])[n] = f2bf(hf);
    }
    __syncthreads();

    const float* px = xg + (size_t)row * 512 + n;
    float xc = px[0];
    float xn = (Tc > 1) ? px[(size_t)BB * 512] : 0.0f;

    int cur = 0;
    for (int t = 0; t < Tc; ++t) {
        // In-loop pin (r13-verified): weights loop-carried, un-reloadable.
#pragma unroll
        for (int j = 0; j < 16; ++j)
            asm volatile("" : "+v"(w[j].x), "+v"(w[j].y), "+v"(w[j].z), "+v"(w[j].w));

        float a = xc;
        xc = xn;
        if (t + 2 < Tc) xn = px[(size_t)(t + 2) * BB * 512];

        // pairs 0..39: one ds_read_b32 (lane l holds pair l) + readlane
        unsigned int hv = hbuf[cur][lane];
#pragma unroll
        for (int j = 0; j < 10; ++j) {
            unsigned int h0 = __builtin_amdgcn_readlane(hv, 4 * j + 0);
            DOT2BS(a, w[j].x, h0);
            unsigned int h1 = __builtin_amdgcn_readlane(hv, 4 * j + 1);
            DOT2BS(a, w[j].y, h1);
            unsigned int h2 = __builtin_amdgcn_readlane(hv, 4 * j + 2);
            DOT2BS(a, w[j].z, h2);
            unsigned int h3 = __builtin_amdgcn_readlane(hv, 4 * j + 3);
            DOT2BS(a, w[j].w, h3);
        }
        // pairs 40..63: 6 uniform ds_read_b128
        {
            const uint4* hb = (const uint4*)hbuf[cur];
#pragma unroll
            for (int j = 10; j < 16; ++j) {
                uint4 hq = hb[j];
                DOT2BF(a, w[j].x, hq.x); DOT2BF(a, w[j].y, hq.y);
                DOT2BF(a, w[j].z, hq.z); DOT2BF(a, w[j].w, hq.w);
            }
        }
        g_lds[n] = a;
        __syncthreads();

        if (n < 128) {
            float i_ = sigm(g_lds[n]);
            float f_ = sigm(g_lds[n + 128]);
            float g_ = tanh_(g_lds[n + 256]);
            float o_ = sigm(g_lds[n + 384]);
            c  = fmaf(f_, c, i_ * g_);
            hf = o_ * tanh_(c);
            unsigned short hb16 = f2bf(hf);
            ((unsigned short*)hbuf[cur ^ 1])[n] = hb16;
            ((unsigned short*)hout)[((size_t)t * BB + row) * 128 + n] = hb16;
        }
        cur ^= 1;
        __syncthreads();
    }
    if (n < 128) {
        cstate[row * 128 + n] = c;
        hstate[row * 128 + n] = hf;
    }
}

// ---------------------------------------------------------------------------
// scan2 (H=64): 256 blocks x 256 thr (4 waves), thread n owns gate-row n.
// Hybrid: pairs 0..19 via readlane, pairs 20..31 via 3 ds_read_b128.
// ---------------------------------------------------------------------------
__global__ __launch_bounds__(256)
__attribute__((amdgpu_waves_per_eu(1, 1)))
void lstm_scan2(
    const float* __restrict__ xg,        // [Tc, BB, 256]
    const unsigned int* __restrict__ Wp, // [256 rows][32 uint] bf16-pairs
    __hip_bfloat16* __restrict__ hout,   // [Tc, BB, 64] bf16
    float* __restrict__ hstate, float* __restrict__ cstate,
    int Tc, int first)
{
    const int n    = threadIdx.x;   // gate-row 0..255
    const int lane = n & 63;
    const int row  = blockIdx.x;
    __shared__ unsigned int hbuf[2][32];
    __shared__ float g_lds[256];

    uint4 w[8];
    {
        const uint4* wr_ = (const uint4*)(Wp + (size_t)n * 32);
#pragma unroll
        for (int j = 0; j < 8; ++j) w[j] = wr_[j];
    }

    float c = 0.0f, hf = 0.0f;
    if (n < 64) {
        c  = first ? 0.0f : cstate[row * 64 + n];
        hf = first ? 0.0f : hstate[row * 64 + n];
        ((unsigned short*)hbuf[0])[n] = f2bf(hf);
    }
    __syncthreads();

    const float* px = xg + (size_t)row * 256 + n;
    float xc = px[0];
    float xn = (Tc > 1) ? px[(size_t)BB * 256] : 0.0f;

    int cur = 0;
    for (int t = 0; t < Tc; ++t) {
#pragma unroll
        for (int j = 0; j < 8; ++j)
            asm volatile("" : "+v"(w[j].x), "+v"(w[j].y), "+v"(w[j].z), "+v"(w[j].w));

        float a = xc;
        xc = xn;
        if (t + 2 < Tc) xn = px[(size_t)(t + 2) * BB * 256];

        unsigned int hv = hbuf[cur][lane & 31];   // 1 ds_read_b32 per wave
#pragma unroll
        for (int j = 0; j < 5; ++j) {             // pairs 0..19
            unsigned int h0 = __builtin_amdgcn_readlane(hv, 4 * j + 0);
            DOT2BS(a, w[j].x, h0);
            unsigned int h1 = __builtin_amdgcn_readlane(hv, 4 * j + 1);
            DOT2BS(a, w[j].y, h1);
            unsigned int h2 = __builtin_amdgcn_readlane(hv, 4 * j + 2);
            DOT2BS(a, w[j].z, h2);
            unsigned int h3 = __builtin_amdgcn_readlane(hv, 4 * j + 3);
            DOT2BS(a, w[j].w, h3);
        }
        {
            const uint4* hb = (const uint4*)hbuf[cur];
#pragma unroll
            for (int j = 5; j < 8; ++j) {         // pairs 20..31
                uint4 hq = hb[j];
                DOT2BF(a, w[j].x, hq.x); DOT2BF(a, w[j].y, hq.y);
                DOT2BF(a, w[j].z, hq.z); DOT2BF(a, w[j].w, hq.w);
            }
        }
        g_lds[n] = a;
        __syncthreads();

        if (n < 64) {
            float i_ = sigm(g_lds[n]);
            float f_ = sigm(g_lds[n + 64]);
            float g_ = tanh_(g_lds[n + 128]);
            float o_ = sigm(g_lds[n + 192]);
            c  = fmaf(f_, c, i_ * g_);
            hf = o_ * tanh_(c);
            unsigned short hb16 = f2bf(hf);
            ((unsigned short*)hbuf[cur ^ 1])[n] = hb16;
            ((unsigned short*)hout)[((size_t)t * BB + row) * 64 + n] = hb16;
        }
        cur ^= 1;
        __syncthreads();
    }
    if (n < 64) {
        cstate[row * 64 + n] = c;
        hstate[row * 64 + n] = hf;
    }
}

// ---------------------------------------------------------------------------
// Layer-3 input GEMM, bf16 X (r13): out[m,0..3] = sum_k X[m,k]*W[n,k] + b
// ---------------------------------------------------------------------------
__global__ __launch_bounds__(256) void gemm_xg3b(
    const __hip_bfloat16* __restrict__ X,  // [M, 64] bf16
    const float* __restrict__ W,           // [4, 64] f32
    const float* __restrict__ b1, const float* __restrict__ b2,
    float* __restrict__ out)               // [M, 4]
{
    __shared__ __align__(16) float ws4[4][64];
    __shared__ float bb[4];
    const int tid = threadIdx.x;
    {
        const int nn = tid >> 6, kk = tid & 63;
        ws4[nn][kk] = W[nn * 64 + kk];
    }
    if (tid < 4) bb[tid] = b1[tid] + b2[tid];
    __syncthreads();

    const int m = blockIdx.x * 256 + tid;
    const uint4* xr = reinterpret_cast<const uint4*>(X + (size_t)m * 64);
    float a0 = bb[0], a1 = bb[1], a2 = bb[2], a3 = bb[3];
#pragma unroll
    for (int kk = 0; kk < 8; ++kk) {       // 8 bf16 per uint4
        uint4 v = xr[kk];
        float xf[8];
        xf[0] = b2f((unsigned short)(v.x & 0xffff));
        xf[1] = b2f((unsigned short)(v.x >> 16));
        xf[2] = b2f((unsigned short)(v.y & 0xffff));
        xf[3] = b2f((unsigned short)(v.y >> 16));
        xf[4] = b2f((unsigned short)(v.z & 0xffff));
        xf[5] = b2f((unsigned short)(v.z >> 16));
        xf[6] = b2f((unsigned short)(v.w & 0xffff));
        xf[7] = b2f((unsigned short)(v.w >> 16));
#pragma unroll
        for (int j = 0; j < 8; ++j) {
            int k = kk * 8 + j;
            a0 = fmaf(xf[j], ws4[0][k], a0);
            a1 = fmaf(xf[j], ws4[1][k], a1);
            a2 = fmaf(xf[j], ws4[2][k], a2);
            a3 = fmaf(xf[j], ws4[3][k], a3);
        }
    }
    float4 o; o.x = a0; o.y = a1; o.z = a2; o.w = a3;
    *reinterpret_cast<float4*>(&out[(size_t)m * 4]) = o;
}

// ---------------------------------------------------------------------------
// Layer-3 scan: 8-deep static prefetch ring (r5, verified).
// ---------------------------------------------------------------------------
__global__ __launch_bounds__(256) void lstm_scan3(
    const float* __restrict__ xg,   // [T, B, 4]
    const float* __restrict__ Whh,  // [4, 1]
    float* __restrict__ out,        // [T, B]
    int T)
{
    const int b = threadIdx.x;
    const float w0 = Whh[0], w1 = Whh[1], w2 = Whh[2], w3 = Whh[3];
    float h = 0.0f, c = 0.0f;
    const float4* p = reinterpret_cast<const float4*>(xg) + b;

    float4 cur[8], nxt[8];
#pragma unroll
    for (int j = 0; j < 8; ++j) cur[j] = p[(size_t)j * BB];

    for (int t0 = 0; t0 < T; t0 += 8) {
#pragma unroll
        for (int j = 0; j < 8; ++j) {
            int tt = t0 + 8 + j;
            if (tt < T) nxt[j] = p[(size_t)tt * BB];
        }
#pragma unroll
        for (int j = 0; j < 8; ++j) {
            float4 g4 = cur[j];
            float gi = fmaf(h, w0, g4.x);
            float gf = fmaf(h, w1, g4.y);
            float gg = fmaf(h, w2, g4.z);
            float go = fmaf(h, w3, g4.w);
            float i_ = sigm(gi);
            float f_ = sigm(gf);
            float g_ = tanh_(gg);
            float o_ = sigm(go);
            c = fmaf(f_, c, i_ * g_);
            h = o_ * tanh_(c);
            out[(size_t)(t0 + j) * BB + b] = h;
        }
#pragma unroll
        for (int j = 0; j < 8; ++j) cur[j] = nxt[j];
    }
}

// ---------------------------------------------------------------------------
extern "C" void kernel_launch(void* const* d_in, const int* in_sizes, int n_in,
                              void* d_out, int out_size, void* d_ws, size_t ws_size,
                              hipStream_t stream) {
    const float* x    = (const float*)d_in[0];
    const float* Wih1 = (const float*)d_in[1];
    const float* Whh1 = (const float*)d_in[2];
    const float* bih1 = (const float*)d_in[3];
    const float* bhh1 = (const float*)d_in[4];
    const float* Wih2 = (const float*)d_in[5];
    const float* Whh2 = (const float*)d_in[6];
    const float* bih2 = (const float*)d_in[7];
    const float* bhh2 = (const float*)d_in[8];
    const float* Wih3 = (const float*)d_in[9];
    const float* Whh3 = (const float*)d_in[10];
    const float* bih3 = (const float*)d_in[11];
    const float* bhh3 = (const float*)d_in[12];
    float* out = (float*)d_out;

    char* ws = (char*)d_ws;
    // Workspace layout, ~187.4 MB total:
    float*          xg1c  = (float*)(ws + 0);                   // [CH,B,512] f32 = 67,108,864
    float*          xg2c  = (float*)(ws + 67108864);            // [CH,B,256] f32 = 33,554,432
    __hip_bfloat16* xb    = (__hip_bfloat16*)(ws + 100663296);  // [T,B,128] bf16 = 33,554,432
    __hip_bfloat16* h1b   = (__hip_bfloat16*)(ws + 134217728);  // [T,B,128] bf16 = 33,554,432
    __hip_bfloat16* h2bb  = (__hip_bfloat16*)(ws + 167772160);  // [T,B,64]  bf16 = 16,777,216
    float*          xg3   = (float*)(ws + 184549376);           // [T,B,4]   f32  =  2,097,152
    __hip_bfloat16* wb1   = (__hip_bfloat16*)(ws + 186646528);  // [512,128] =   131,072
    __hip_bfloat16* whb1  = (__hip_bfloat16*)(ws + 186777600);  // [512,128] =   131,072
    __hip_bfloat16* wb2   = (__hip_bfloat16*)(ws + 186908672);  // [256,128] =    65,536
    __hip_bfloat16* whb2  = (__hip_bfloat16*)(ws + 186974208);  // [256,64]  =    32,768
    float*          bias1 = (float*)(ws + 187006976);           //     2,048
    float*          bias2 = (float*)(ws + 187009024);           //     1,024
    float*          bias3 = (float*)(ws + 187010048);           //        64
    float*          st1h  = (float*)(ws + 187010112);           // [B,128] f32
    float*          st1c  = (float*)(ws + 187141184);
    float*          st2h  = (float*)(ws + 187272256);           // [B,64] f32
    float*          st2c  = (float*)(ws + 187337792);

    // ---- P0: conversions / bias prep ----
    cvt_pad<<<4096, 256, 0, stream>>>(x, xb, T_TOT * BB, 97);
    cvt_pad<<<256, 256, 0, stream>>>(Wih1, wb1, 512, 97);
    cvt_plain<<<256, 256, 0, stream>>>(Whh1, whb1, 512 * 128);
    cvt_plain<<<128, 256, 0, stream>>>(Wih2, wb2, 256 * 128);
    cvt_plain<<<64, 256, 0, stream>>>(Whh2, whb2, 256 * 64);
    addvec<<<2, 256, 0, stream>>>(bih1, bhh1, bias1, 512);
    addvec<<<1, 256, 0, stream>>>(bih2, bhh2, bias2, 256);

    // ---- Layer 1 (chunked over T) ----
    for (int c0 = 0; c0 < NCH; ++c0) {
        gemm_mfma<<<dim3(CH * BB / 128, 512 / 128), 256, 0, stream>>>(
            xb + (size_t)c0 * CH * BB * 128, wb1, bias1, xg1c, 512);
        lstm_scan1<<<BB, 512, 0, stream>>>(
            xg1c, (const unsigned int*)whb1,
            h1b + (size_t)c0 * CH * BB * 128, st1h, st1c, CH, c0 == 0);
    }
    // ---- Layer 2 (chunked over T) ----
    for (int c0 = 0; c0 < NCH; ++c0) {
        gemm_mfma<<<dim3(CH * BB / 128, 256 / 128), 256, 0, stream>>>(
            h1b + (size_t)c0 * CH * BB * 128, wb2, bias2, xg2c, 256);
        lstm_scan2<<<BB, 256, 0, stream>>>(
            xg2c, (const unsigned int*)whb2,
            h2bb + (size_t)c0 * CH * BB * 64, st2h, st2c, CH, c0 == 0);
    }
    // ---- Layer 3 ----
    gemm_xg3b<<<T_TOT * BB / 256, 256, 0, stream>>>(h2bb, Wih3, bih3, bhh3, xg3);
    lstm_scan3<<<1, 256, 0, stream>>>(xg3, Whh3, out, T_TOT);
}

// Round 19
// 765.438 us; speedup vs baseline: 1.1883x; 1.1653x over previous
//
#include <hip/hip_runtime.h>
#include <hip/hip_bf16.h>

// 3-layer stacked LSTM forward (eval). Round 19 = r18 with the wave-4 L3
// readlane bug fixed: __builtin_amdgcn_readlane(float,..) did an implicit
// float->uint VALUE conversion (truncation) -> gate preacts became integers
// -> absmax 0.218. Fix: readlane_f bit-casts through u32.
//  - scan1: byte-identical r13 (94us/chunk local optimum, weights resident).
//  - scan23: r13 scan2 (waves 0-3) + layer-3 fused on wave 4 (f32 LDS h2 ring,
//    shfl_xor reduce, scalar L3 cell incl. h3*Whh3). Kills gemm_xg3b +
//    lstm_scan3 + the h2 global round-trip.
//  - prep_small: 6 small cvt/addvec kernels merged into one.
// T=512, B=256, IN=97(pad128), H1=128, H2=64, H3=1.

#define T_TOT 512
#define BB    256
#define CH    128
#define NCH   4

typedef __attribute__((ext_vector_type(8))) short  short8v;   // 8 bf16
typedef __attribute__((ext_vector_type(4))) float  float4v;   // MFMA acc

// acc += w.lo*h.lo + w.hi*h.hi (VOP3P, verified r5+)
#define DOT2BF(acc, wu, hu) \
    asm("v_dot2_f32_bf16 %0, %1, %2, %0" : "+v"(acc) : "v"(wu), "v"(hu))

__device__ __forceinline__ float sigm(float x) {
    float e = __expf(-x);
    return __builtin_amdgcn_rcpf(1.0f + e);
}
__device__ __forceinline__ float tanh_(float x) {
    float e = __expf(2.0f * x);
    return 1.0f - 2.0f * __builtin_amdgcn_rcpf(1.0f + e);
}
__device__ __forceinline__ unsigned short f2bf(float x) {
    __hip_bfloat16 b = __float2bfloat16(x);
    return __builtin_bit_cast(unsigned short, b);
}
// Bit-exact float lane broadcast (r18 bug: value-converting readlane).
__device__ __forceinline__ float readlane_f(float v, int l) {
    unsigned int u = __builtin_amdgcn_readlane(__builtin_bit_cast(unsigned int, v), l);
    return __builtin_bit_cast(float, u);
}

// ---------------------------------------------------------------------------
// Big input conversion (x -> bf16 padded).
// ---------------------------------------------------------------------------
__global__ __launch_bounds__(256) void cvt_pad_x(
    const float* __restrict__ in, __hip_bfloat16* __restrict__ out)
{
    int total = T_TOT * BB * 128;
    for (int idx = blockIdx.x * 256 + threadIdx.x; idx < total; idx += gridDim.x * 256) {
        int r = idx >> 7, c = idx & 127;
        float v = (c < 97) ? in[(size_t)r * 97 + c] : 0.0f;
        out[idx] = __float2bfloat16(v);
    }
}

// ---------------------------------------------------------------------------
// prep_small: all weight/bias conversions in one kernel (180,992 elems).
// ---------------------------------------------------------------------------
__global__ __launch_bounds__(256) void prep_small(
    const float* __restrict__ Wih1, const float* __restrict__ Whh1,
    const float* __restrict__ Wih2, const float* __restrict__ Whh2,
    const float* __restrict__ bih1, const float* __restrict__ bhh1,
    const float* __restrict__ bih2, const float* __restrict__ bhh2,
    __hip_bfloat16* __restrict__ wb1, __hip_bfloat16* __restrict__ whb1,
    __hip_bfloat16* __restrict__ wb2, __hip_bfloat16* __restrict__ whb2,
    float* __restrict__ bias1, float* __restrict__ bias2)
{
    int idx = blockIdx.x * 256 + threadIdx.x;
    if (idx < 65536) {
        int r = idx >> 7, c = idx & 127;
        float v = (c < 97) ? Wih1[(size_t)r * 97 + c] : 0.0f;
        wb1[idx] = __float2bfloat16(v);
    } else if (idx < 131072) {
        int i = idx - 65536;
        whb1[i] = __float2bfloat16(Whh1[i]);
    } else if (idx < 163840) {
        int i = idx - 131072;
        wb2[i] = __float2bfloat16(Wih2[i]);
    } else if (idx < 180224) {
        int i = idx - 163840;
        whb2[i] = __float2bfloat16(Whh2[i]);
    } else if (idx < 180736) {
        int i = idx - 180224;
        bias1[i] = bih1[i] + bhh1[i];
    } else if (idx < 180992) {
        int i = idx - 180736;
        bias2[i] = bih2[i] + bhh2[i];
    }
}

// ---------------------------------------------------------------------------
// bf16 MFMA GEMM (r4, verified): C[M,N] = A[M,128] * W[N,128]^T + bias
// ---------------------------------------------------------------------------
__global__ __launch_bounds__(256) void gemm_mfma(
    const __hip_bfloat16* __restrict__ A,
    const __hip_bfloat16* __restrict__ W,
    const float* __restrict__ bias,
    float* __restrict__ C, int N)
{
    __shared__ __hip_bfloat16 At[128 * 128];   // 32 KB

    const int tid  = threadIdx.x;
    const int lane = tid & 63;
    const int wid  = tid >> 6;
    const int m0   = blockIdx.x * 128;
    const int n0   = blockIdx.y * 128;
    const int wr   = wid >> 1;
    const int wc   = wid & 1;

    short8v bfrag[4][4];  // [nf][kf]
    {
        const char* Wg = (const char*)W;
#pragma unroll
        for (int nf = 0; nf < 4; ++nf) {
            int row = n0 + wc * 64 + nf * 16 + (lane & 15);
#pragma unroll
            for (int kf = 0; kf < 4; ++kf) {
                int colb = (kf * 32 + (lane >> 4) * 8) * 2;
                bfrag[nf][kf] = *(const short8v*)(Wg + (size_t)row * 256 + colb);
            }
        }
    }
    {
        const char* Ag = (const char*)(A + (size_t)m0 * 128);
        char* As = (char*)At;
#pragma unroll
        for (int r2 = 0; r2 < 8; ++r2) {
            int off = r2 * 4096 + tid * 16;
            int row = off >> 8;
            int bir = off & 255;
            short8v v = *(const short8v*)(Ag + (size_t)row * 256 + bir);
            int sw = bir ^ ((row & 7) << 4);
            *(short8v*)(As + row * 256 + sw) = v;
        }
    }
    __syncthreads();

    float4v acc[4][4] = {};
#pragma unroll
    for (int kf = 0; kf < 4; ++kf) {
        short8v af[4];
#pragma unroll
        for (int mf = 0; mf < 4; ++mf) {
            int row   = wr * 64 + mf * 16 + (lane & 15);
            int kbyte = kf * 64 + (lane >> 4) * 16;
            int sw    = kbyte ^ ((row & 7) << 4);
            af[mf] = *(const short8v*)((const char*)At + row * 256 + sw);
        }
#pragma unroll
        for (int mf = 0; mf < 4; ++mf)
#pragma unroll
            for (int nf = 0; nf < 4; ++nf)
                acc[mf][nf] = __builtin_amdgcn_mfma_f32_16x16x32_bf16(
                    af[mf], bfrag[nf][kf], acc[mf][nf], 0, 0, 0);
    }

#pragma unroll
    for (int nf = 0; nf < 4; ++nf) {
        int col = n0 + wc * 64 + nf * 16 + (lane & 15);
        float bv = bias[col];
#pragma unroll
        for (int mf = 0; mf < 4; ++mf) {
            int rbase = m0 + wr * 64 + mf * 16 + (lane >> 4) * 4;
#pragma unroll
            for (int r = 0; r < 4; ++r)
                C[(size_t)(rbase + r) * N + col] = acc[mf][nf][r] + bv;
        }
    }
}

// ---------------------------------------------------------------------------
// scan1 (H=128): byte-identical to r13 (94us/chunk local optimum).
// ---------------------------------------------------------------------------
__global__ __launch_bounds__(512)
__attribute__((amdgpu_waves_per_eu(2, 2)))
void lstm_scan1(
    const float* __restrict__ xg,        // [Tc, BB, 512] f32, bias included
    const unsigned int* __restrict__ Wp, // [512 rows][64 uint] bf16-pairs
    __hip_bfloat16* __restrict__ hout,   // [Tc, BB, 128]
    float* __restrict__ hstate, float* __restrict__ cstate,
    int Tc, int first)
{
    const int n   = threadIdx.x;     // gate-row 0..511
    const int row = blockIdx.x;
    __shared__ unsigned int hbuf[2][64];   // 128 bf16, double-buffered
    __shared__ float g_lds[512];

    uint4 w[16];   // 64 VGPR of weights, static-indexed
    {
        const uint4* wr_ = (const uint4*)(Wp + (size_t)n * 64);
#pragma unroll
        for (int j = 0; j < 16; ++j) w[j] = wr_[j];
    }

    float c = 0.0f, hf = 0.0f;
    if (n < 128) {
        c  = first ? 0.0f : cstate[row * 128 + n];
        hf = first ? 0.0f : hstate[row * 128 + n];
        ((unsigned short*)hbuf[0])[n] = f2bf(hf);
    }
    __syncthreads();

    const float* px = xg + (size_t)row * 512 + n;
    float xc = px[0];
    float xn = (Tc > 1) ? px[(size_t)BB * 512] : 0.0f;

    int cur = 0;
    for (int t = 0; t < Tc; ++t) {
        // In-loop pin (r13-verified): weights loop-carried, un-reloadable.
#pragma unroll
        for (int j = 0; j < 16; ++j)
            asm volatile("" : "+v"(w[j].x), "+v"(w[j].y), "+v"(w[j].z), "+v"(w[j].w));

        float a = xc;
        xc = xn;
        if (t + 2 < Tc) xn = px[(size_t)(t + 2) * BB * 512];

        const uint4* hb = (const uint4*)hbuf[cur];   // wave-uniform (broadcast)
#pragma unroll
        for (int j = 0; j < 16; ++j) {
            uint4 hv = hb[j];
            DOT2BF(a, w[j].x, hv.x); DOT2BF(a, w[j].y, hv.y);
            DOT2BF(a, w[j].z, hv.z); DOT2BF(a, w[j].w, hv.w);
        }
        g_lds[n] = a;
        __syncthreads();

        if (n < 128) {
            float i_ = sigm(g_lds[n]);
            float f_ = sigm(g_lds[n + 128]);
            float g_ = tanh_(g_lds[n + 256]);
            float o_ = sigm(g_lds[n + 384]);
            c  = fmaf(f_, c, i_ * g_);
            hf = o_ * tanh_(c);
            unsigned short hb16 = f2bf(hf);
            ((unsigned short*)hbuf[cur ^ 1])[n] = hb16;
            ((unsigned short*)hout)[((size_t)t * BB + row) * 128 + n] = hb16;
        }
        cur ^= 1;
        __syncthreads();
    }
    if (n < 128) {
        cstate[row * 128 + n] = c;
        hstate[row * 128 + n] = hf;
    }
}

// ---------------------------------------------------------------------------
// scan23: layer-2 scan (waves 0-3, r13 scan2 math) + layer-3 fused on wave 4.
// ---------------------------------------------------------------------------
__global__ __launch_bounds__(320)
__attribute__((amdgpu_waves_per_eu(1, 1)))
void lstm_scan23(
    const float* __restrict__ xg,        // [Tc, BB, 256] f32, bias included
    const unsigned int* __restrict__ Wp, // [256 rows][32 uint] bf16-pairs
    float* __restrict__ hstate, float* __restrict__ cstate,   // L2 state
    const float* __restrict__ Wx3,       // [4,64] f32 (raw Wih3)
    const float* __restrict__ Wh3,       // [4,1]  f32 (raw Whh3)
    const float* __restrict__ bih3, const float* __restrict__ bhh3,
    float* __restrict__ st3h, float* __restrict__ st3c,       // [B] L3 state
    float* __restrict__ out,             // [T, BB]
    int Tc, int first, int tbase)
{
    const int tid = threadIdx.x;
    const int row = blockIdx.x;
    __shared__ unsigned int hbuf[2][32];   // h2 bf16 pairs, dbuf
    __shared__ float g_lds[256];
    __shared__ float h2f[2][64];           // h2 f32 ring for L3

    if (tid < 256) {
        // ================= waves 0-3: layer-2 scan (r13) =================
        const int n = tid;    // gate-row 0..255

        uint4 w[8];
        {
            const uint4* wr_ = (const uint4*)(Wp + (size_t)n * 32);
#pragma unroll
            for (int j = 0; j < 8; ++j) w[j] = wr_[j];
        }

        float c = 0.0f, hf = 0.0f;
        if (n < 64) {
            c  = first ? 0.0f : cstate[row * 64 + n];
            hf = first ? 0.0f : hstate[row * 64 + n];
            ((unsigned short*)hbuf[0])[n] = f2bf(hf);
            h2f[0][n] = hf;
        }
        __syncthreads();

        const float* px = xg + (size_t)row * 256 + n;
        float xc = px[0];
        float xn = (Tc > 1) ? px[(size_t)BB * 256] : 0.0f;

        int cur = 0;
        for (int t = 0; t < Tc; ++t) {
#pragma unroll
            for (int j = 0; j < 8; ++j)
                asm volatile("" : "+v"(w[j].x), "+v"(w[j].y), "+v"(w[j].z), "+v"(w[j].w));

            float a = xc;
            xc = xn;
            if (t + 2 < Tc) xn = px[(size_t)(t + 2) * BB * 256];

            const uint4* hb = (const uint4*)hbuf[cur];
#pragma unroll
            for (int j = 0; j < 8; ++j) {
                uint4 hv = hb[j];
                DOT2BF(a, w[j].x, hv.x); DOT2BF(a, w[j].y, hv.y);
                DOT2BF(a, w[j].z, hv.z); DOT2BF(a, w[j].w, hv.w);
            }
            g_lds[n] = a;
            __syncthreads();

            if (n < 64) {
                float i_ = sigm(g_lds[n]);
                float f_ = sigm(g_lds[n + 64]);
                float g_ = tanh_(g_lds[n + 128]);
                float o_ = sigm(g_lds[n + 192]);
                c  = fmaf(f_, c, i_ * g_);
                hf = o_ * tanh_(c);
                ((unsigned short*)hbuf[cur ^ 1])[n] = f2bf(hf);
                h2f[cur ^ 1][n] = hf;
            }
            cur ^= 1;
            __syncthreads();
        }
        if (n < 64) {
            cstate[row * 64 + n] = c;
            hstate[row * 64 + n] = hf;
        }
    } else {
        // ================= wave 4: layer 3 (H=1) =================
        const int lane = tid - 256;      // 0..63
        const int g    = lane >> 4;      // gate 0..3
        const int i    = lane & 15;      // element group 0..15

        float4 w3 = *(const float4*)(Wx3 + g * 64 + 4 * i);
        float b3[4], wh3[4];
#pragma unroll
        for (int k = 0; k < 4; ++k) { b3[k] = bih3[k] + bhh3[k]; wh3[k] = Wh3[k]; }
        float h3 = first ? 0.0f : st3h[row];
        float c3 = first ? 0.0f : st3c[row];

        __syncthreads();   // matches scan-side init barrier

        int cur = 0;
        for (int t = 0; t < Tc; ++t) {
            if (t >= 1) {
                float4 hv = *(const float4*)(&h2f[cur][4 * i]);
                float p = hv.x * w3.x;
                p = fmaf(hv.y, w3.y, p);
                p = fmaf(hv.z, w3.z, p);
                p = fmaf(hv.w, w3.w, p);
                p += __shfl_xor(p, 1);
                p += __shfl_xor(p, 2);
                p += __shfl_xor(p, 4);
                p += __shfl_xor(p, 8);
                float s0 = readlane_f(p, 0);
                float s1 = readlane_f(p, 16);
                float s2 = readlane_f(p, 32);
                float s3 = readlane_f(p, 48);
                float gi  = fmaf(h3, wh3[0], s0 + b3[0]);
                float gf  = fmaf(h3, wh3[1], s1 + b3[1]);
                float gg_ = fmaf(h3, wh3[2], s2 + b3[2]);
                float go  = fmaf(h3, wh3[3], s3 + b3[3]);
                float i_ = sigm(gi);
                float f_ = sigm(gf);
                float g_ = tanh_(gg_);
                float o_ = sigm(go);
                c3 = fmaf(f_, c3, i_ * g_);
                h3 = o_ * tanh_(c3);
                if (lane == 0)
                    out[(size_t)(tbase + t - 1) * BB + row] = h3;
            }
            __syncthreads();   // barrier 1
            __syncthreads();   // barrier 2
            cur ^= 1;
        }
        // tail: out[tbase+Tc-1] from h2f[cur] (last step's h2)
        {
            float4 hv = *(const float4*)(&h2f[cur][4 * i]);
            float p = hv.x * w3.x;
            p = fmaf(hv.y, w3.y, p);
            p = fmaf(hv.z, w3.z, p);
            p = fmaf(hv.w, w3.w, p);
            p += __shfl_xor(p, 1);
            p += __shfl_xor(p, 2);
            p += __shfl_xor(p, 4);
            p += __shfl_xor(p, 8);
            float s0 = readlane_f(p, 0);
            float s1 = readlane_f(p, 16);
            float s2 = readlane_f(p, 32);
            float s3 = readlane_f(p, 48);
            float gi  = fmaf(h3, wh3[0], s0 + b3[0]);
            float gf  = fmaf(h3, wh3[1], s1 + b3[1]);
            float gg_ = fmaf(h3, wh3[2], s2 + b3[2]);
            float go  = fmaf(h3, wh3[3], s3 + b3[3]);
            float i_ = sigm(gi);
            float f_ = sigm(gf);
            float g_ = tanh_(gg_);
            float o_ = sigm(go);
            c3 = fmaf(f_, c3, i_ * g_);
            h3 = o_ * tanh_(c3);
            if (lane == 0) {
                out[(size_t)(tbase + Tc - 1) * BB + row] = h3;
                st3h[row] = h3;
                st3c[row] = c3;
            }
        }
    }
}

// ---------------------------------------------------------------------------
extern "C" void kernel_launch(void* const* d_in, const int* in_sizes, int n_in,
                              void* d_out, int out_size, void* d_ws, size_t ws_size,
                              hipStream_t stream) {
    const float* x    = (const float*)d_in[0];
    const float* Wih1 = (const float*)d_in[1];
    const float* Whh1 = (const float*)d_in[2];
    const float* bih1 = (const float*)d_in[3];
    const float* bhh1 = (const float*)d_in[4];
    const float* Wih2 = (const float*)d_in[5];
    const float* Whh2 = (const float*)d_in[6];
    const float* bih2 = (const float*)d_in[7];
    const float* bhh2 = (const float*)d_in[8];
    const float* Wih3 = (const float*)d_in[9];
    const float* Whh3 = (const float*)d_in[10];
    const float* bih3 = (const float*)d_in[11];
    const float* bhh3 = (const float*)d_in[12];
    float* out = (float*)d_out;

    char* ws = (char*)d_ws;
    // Workspace layout, ~168.5 MB total:
    float*          xg1c  = (float*)(ws + 0);                   // [CH,B,512] f32 = 67,108,864
    float*          xg2c  = (float*)(ws + 67108864);            // [CH,B,256] f32 = 33,554,432
    __hip_bfloat16* xb    = (__hip_bfloat16*)(ws + 100663296);  // [T,B,128] bf16 = 33,554,432
    __hip_bfloat16* h1b   = (__hip_bfloat16*)(ws + 134217728);  // [T,B,128] bf16 = 33,554,432
    __hip_bfloat16* wb1   = (__hip_bfloat16*)(ws + 167772160);  //   131,072
    __hip_bfloat16* whb1  = (__hip_bfloat16*)(ws + 167903232);  //   131,072
    __hip_bfloat16* wb2   = (__hip_bfloat16*)(ws + 168034304);  //    65,536
    __hip_bfloat16* whb2  = (__hip_bfloat16*)(ws + 168099840);  //    32,768
    float*          bias1 = (float*)(ws + 168132608);           //     2,048
    float*          bias2 = (float*)(ws + 168134656);           //     1,024
    float*          st1h  = (float*)(ws + 168135680);           //   131,072
    float*          st1c  = (float*)(ws + 168266752);           //   131,072
    float*          st2h  = (float*)(ws + 168397824);           //    65,536
    float*          st2c  = (float*)(ws + 168463360);           //    65,536
    float*          st3h  = (float*)(ws + 168528896);           //     1,024
    float*          st3c  = (float*)(ws + 168529920);           //     1,024

    // ---- P0: conversions / bias prep (2 launches) ----
    cvt_pad_x<<<4096, 256, 0, stream>>>(x, xb);
    prep_small<<<708, 256, 0, stream>>>(
        Wih1, Whh1, Wih2, Whh2, bih1, bhh1, bih2, bhh2,
        wb1, whb1, wb2, whb2, bias1, bias2);

    // ---- Layer 1 (chunked over T) ----
    for (int c0 = 0; c0 < NCH; ++c0) {
        gemm_mfma<<<dim3(CH * BB / 128, 512 / 128), 256, 0, stream>>>(
            xb + (size_t)c0 * CH * BB * 128, wb1, bias1, xg1c, 512);
        lstm_scan1<<<BB, 512, 0, stream>>>(
            xg1c, (const unsigned int*)whb1,
            h1b + (size_t)c0 * CH * BB * 128, st1h, st1c, CH, c0 == 0);
    }
    // ---- Layers 2+3 (chunked over T; L3 fused on wave 4) ----
    for (int c0 = 0; c0 < NCH; ++c0) {
        gemm_mfma<<<dim3(CH * BB / 128, 256 / 128), 256, 0, stream>>>(
            h1b + (size_t)c0 * CH * BB * 128, wb2, bias2, xg2c, 256);
        lstm_scan23<<<BB, 320, 0, stream>>>(
            xg2c, (const unsigned int*)whb2, st2h, st2c,
            Wih3, Whh3, bih3, bhh3, st3h, st3c, out,
            CH, c0 == 0, c0 * CH);
    }
}

// Round 20
// 723.611 us; speedup vs baseline: 1.2570x; 1.0578x over previous
//
#include <hip/hip_runtime.h>
#include <hip/hip_bf16.h>

// 3-layer stacked LSTM forward (eval). Round 20 = r19 (765us) with NCH=2
// (fewer chunk boundaries / dispatches; xg2 aliases the xg1 region -- phases
// are strictly sequential on one stream). All kernel math byte-identical to
// r19: scan1 = r13 local optimum (DS-pipe bound, 87% util), scan23 = L2 scan
// + fused wave-4 L3, gemm_mfma = r4-verified bf16 MFMA.
// Workspace: 134.2(xg1/xg2 alias) + 33.6(xb) + 33.6(h1b) + ~0.5 = 202MB
// (<= 203.4MB proven in r3).
// T=512, B=256, IN=97(pad128), H1=128, H2=64, H3=1.

#define T_TOT 512
#define BB    256
#define CH    256
#define NCH   2

typedef __attribute__((ext_vector_type(8))) short  short8v;   // 8 bf16
typedef __attribute__((ext_vector_type(4))) float  float4v;   // MFMA acc

// acc += w.lo*h.lo + w.hi*h.hi (VOP3P, verified r5+)
#define DOT2BF(acc, wu, hu) \
    asm("v_dot2_f32_bf16 %0, %1, %2, %0" : "+v"(acc) : "v"(wu), "v"(hu))

__device__ __forceinline__ float sigm(float x) {
    float e = __expf(-x);
    return __builtin_amdgcn_rcpf(1.0f + e);
}
__device__ __forceinline__ float tanh_(float x) {
    float e = __expf(2.0f * x);
    return 1.0f - 2.0f * __builtin_amdgcn_rcpf(1.0f + e);
}
__device__ __forceinline__ unsigned short f2bf(float x) {
    __hip_bfloat16 b = __float2bfloat16(x);
    return __builtin_bit_cast(unsigned short, b);
}
// Bit-exact float lane broadcast (r18 lesson: plain readlane VALUE-converts).
__device__ __forceinline__ float readlane_f(float v, int l) {
    unsigned int u = __builtin_amdgcn_readlane(__builtin_bit_cast(unsigned int, v), l);
    return __builtin_bit_cast(float, u);
}

// ---------------------------------------------------------------------------
// Big input conversion (x -> bf16 padded).
// ---------------------------------------------------------------------------
__global__ __launch_bounds__(256) void cvt_pad_x(
    const float* __restrict__ in, __hip_bfloat16* __restrict__ out)
{
    int total = T_TOT * BB * 128;
    for (int idx = blockIdx.x * 256 + threadIdx.x; idx < total; idx += gridDim.x * 256) {
        int r = idx >> 7, c = idx & 127;
        float v = (c < 97) ? in[(size_t)r * 97 + c] : 0.0f;
        out[idx] = __float2bfloat16(v);
    }
}

// ---------------------------------------------------------------------------
// prep_small: all weight/bias conversions in one kernel (180,992 elems).
// ---------------------------------------------------------------------------
__global__ __launch_bounds__(256) void prep_small(
    const float* __restrict__ Wih1, const float* __restrict__ Whh1,
    const float* __restrict__ Wih2, const float* __restrict__ Whh2,
    const float* __restrict__ bih1, const float* __restrict__ bhh1,
    const float* __restrict__ bih2, const float* __restrict__ bhh2,
    __hip_bfloat16* __restrict__ wb1, __hip_bfloat16* __restrict__ whb1,
    __hip_bfloat16* __restrict__ wb2, __hip_bfloat16* __restrict__ whb2,
    float* __restrict__ bias1, float* __restrict__ bias2)
{
    int idx = blockIdx.x * 256 + threadIdx.x;
    if (idx < 65536) {
        int r = idx >> 7, c = idx & 127;
        float v = (c < 97) ? Wih1[(size_t)r * 97 + c] : 0.0f;
        wb1[idx] = __float2bfloat16(v);
    } else if (idx < 131072) {
        int i = idx - 65536;
        whb1[i] = __float2bfloat16(Whh1[i]);
    } else if (idx < 163840) {
        int i = idx - 131072;
        wb2[i] = __float2bfloat16(Wih2[i]);
    } else if (idx < 180224) {
        int i = idx - 163840;
        whb2[i] = __float2bfloat16(Whh2[i]);
    } else if (idx < 180736) {
        int i = idx - 180224;
        bias1[i] = bih1[i] + bhh1[i];
    } else if (idx < 180992) {
        int i = idx - 180736;
        bias2[i] = bih2[i] + bhh2[i];
    }
}

// ---------------------------------------------------------------------------
// bf16 MFMA GEMM (r4, verified): C[M,N] = A[M,128] * W[N,128]^T + bias
// ---------------------------------------------------------------------------
__global__ __launch_bounds__(256) void gemm_mfma(
    const __hip_bfloat16* __restrict__ A,
    const __hip_bfloat16* __restrict__ W,
    const float* __restrict__ bias,
    float* __restrict__ C, int N)
{
    __shared__ __hip_bfloat16 At[128 * 128];   // 32 KB

    const int tid  = threadIdx.x;
    const int lane = tid & 63;
    const int wid  = tid >> 6;
    const int m0   = blockIdx.x * 128;
    const int n0   = blockIdx.y * 128;
    const int wr   = wid >> 1;
    const int wc   = wid & 1;

    short8v bfrag[4][4];  // [nf][kf]
    {
        const char* Wg = (const char*)W;
#pragma unroll
        for (int nf = 0; nf < 4; ++nf) {
            int row = n0 + wc * 64 + nf * 16 + (lane & 15);
#pragma unroll
            for (int kf = 0; kf < 4; ++kf) {
                int colb = (kf * 32 + (lane >> 4) * 8) * 2;
                bfrag[nf][kf] = *(const short8v*)(Wg + (size_t)row * 256 + colb);
            }
        }
    }
    {
        const char* Ag = (const char*)(A + (size_t)m0 * 128);
        char* As = (char*)At;
#pragma unroll
        for (int r2 = 0; r2 < 8; ++r2) {
            int off = r2 * 4096 + tid * 16;
            int row = off >> 8;
            int bir = off & 255;
            short8v v = *(const short8v*)(Ag + (size_t)row * 256 + bir);
            int sw = bir ^ ((row & 7) << 4);
            *(short8v*)(As + row * 256 + sw) = v;
        }
    }
    __syncthreads();

    float4v acc[4][4] = {};
#pragma unroll
    for (int kf = 0; kf < 4; ++kf) {
        short8v af[4];
#pragma unroll
        for (int mf = 0; mf < 4; ++mf) {
            int row   = wr * 64 + mf * 16 + (lane & 15);
            int kbyte = kf * 64 + (lane >> 4) * 16;
            int sw    = kbyte ^ ((row & 7) << 4);
            af[mf] = *(const short8v*)((const char*)At + row * 256 + sw);
        }
#pragma unroll
        for (int mf = 0; mf < 4; ++mf)
#pragma unroll
            for (int nf = 0; nf < 4; ++nf)
                acc[mf][nf] = __builtin_amdgcn_mfma_f32_16x16x32_bf16(
                    af[mf], bfrag[nf][kf], acc[mf][nf], 0, 0, 0);
    }

#pragma unroll
    for (int nf = 0; nf < 4; ++nf) {
        int col = n0 + wc * 64 + nf * 16 + (lane & 15);
        float bv = bias[col];
#pragma unroll
        for (int mf = 0; mf < 4; ++mf) {
            int rbase = m0 + wr * 64 + mf * 16 + (lane >> 4) * 4;
#pragma unroll
            for (int r = 0; r < 4; ++r)
                C[(size_t)(rbase + r) * N + col] = acc[mf][nf][r] + bv;
        }
    }
}

// ---------------------------------------------------------------------------
// scan1 (H=128): byte-identical to r13/r19 (DS-pipe-bound local optimum).
// ---------------------------------------------------------------------------
__global__ __launch_bounds__(512)
__attribute__((amdgpu_waves_per_eu(2, 2)))
void lstm_scan1(
    const float* __restrict__ xg,        // [Tc, BB, 512] f32, bias included
    const unsigned int* __restrict__ Wp, // [512 rows][64 uint] bf16-pairs
    __hip_bfloat16* __restrict__ hout,   // [Tc, BB, 128]
    float* __restrict__ hstate, float* __restrict__ cstate,
    int Tc, int first)
{
    const int n   = threadIdx.x;     // gate-row 0..511
    const int row = blockIdx.x;
    __shared__ unsigned int hbuf[2][64];   // 128 bf16, double-buffered
    __shared__ float g_lds[512];

    uint4 w[16];   // 64 VGPR of weights, static-indexed
    {
        const uint4* wr_ = (const uint4*)(Wp + (size_t)n * 64);
#pragma unroll
        for (int j = 0; j < 16; ++j) w[j] = wr_[j];
    }

    float c = 0.0f, hf = 0.0f;
    if (n < 128) {
        c  = first ? 0.0f : cstate[row * 128 + n];
        hf = first ? 0.0f : hstate[row * 128 + n];
        ((unsigned short*)hbuf[0])[n] = f2bf(hf);
    }
    __syncthreads();

    const float* px = xg + (size_t)row * 512 + n;
    float xc = px[0];
    float xn = (Tc > 1) ? px[(size_t)BB * 512] : 0.0f;

    int cur = 0;
    for (int t = 0; t < Tc; ++t) {
        // In-loop pin (r13-verified): weights loop-carried, un-reloadable.
#pragma unroll
        for (int j = 0; j < 16; ++j)
            asm volatile("" : "+v"(w[j].x), "+v"(w[j].y), "+v"(w[j].z), "+v"(w[j].w));

        float a = xc;
        xc = xn;
        if (t + 2 < Tc) xn = px[(size_t)(t + 2) * BB * 512];

        const uint4* hb = (const uint4*)hbuf[cur];   // wave-uniform (broadcast)
#pragma unroll
        for (int j = 0; j < 16; ++j) {
            uint4 hv = hb[j];
            DOT2BF(a, w[j].x, hv.x); DOT2BF(a, w[j].y, hv.y);
            DOT2BF(a, w[j].z, hv.z); DOT2BF(a, w[j].w, hv.w);
        }
        g_lds[n] = a;
        __syncthreads();

        if (n < 128) {
            float i_ = sigm(g_lds[n]);
            float f_ = sigm(g_lds[n + 128]);
            float g_ = tanh_(g_lds[n + 256]);
            float o_ = sigm(g_lds[n + 384]);
            c  = fmaf(f_, c, i_ * g_);
            hf = o_ * tanh_(c);
            unsigned short hb16 = f2bf(hf);
            ((unsigned short*)hbuf[cur ^ 1])[n] = hb16;
            ((unsigned short*)hout)[((size_t)t * BB + row) * 128 + n] = hb16;
        }
        cur ^= 1;
        __syncthreads();
    }
    if (n < 128) {
        cstate[row * 128 + n] = c;
        hstate[row * 128 + n] = hf;
    }
}

// ---------------------------------------------------------------------------
// scan23: layer-2 scan (waves 0-3) + layer-3 fused on wave 4 (r19-verified).
// ---------------------------------------------------------------------------
__global__ __launch_bounds__(320)
__attribute__((amdgpu_waves_per_eu(1, 1)))
void lstm_scan23(
    const float* __restrict__ xg,        // [Tc, BB, 256] f32, bias included
    const unsigned int* __restrict__ Wp, // [256 rows][32 uint] bf16-pairs
    float* __restrict__ hstate, float* __restrict__ cstate,   // L2 state
    const float* __restrict__ Wx3,       // [4,64] f32 (raw Wih3)
    const float* __restrict__ Wh3,       // [4,1]  f32 (raw Whh3)
    const float* __restrict__ bih3, const float* __restrict__ bhh3,
    float* __restrict__ st3h, float* __restrict__ st3c,       // [B] L3 state
    float* __restrict__ out,             // [T, BB]
    int Tc, int first, int tbase)
{
    const int tid = threadIdx.x;
    const int row = blockIdx.x;
    __shared__ unsigned int hbuf[2][32];   // h2 bf16 pairs, dbuf
    __shared__ float g_lds[256];
    __shared__ float h2f[2][64];           // h2 f32 ring for L3

    if (tid < 256) {
        // ================= waves 0-3: layer-2 scan =================
        const int n = tid;    // gate-row 0..255

        uint4 w[8];
        {
            const uint4* wr_ = (const uint4*)(Wp + (size_t)n * 32);
#pragma unroll
            for (int j = 0; j < 8; ++j) w[j] = wr_[j];
        }

        float c = 0.0f, hf = 0.0f;
        if (n < 64) {
            c  = first ? 0.0f : cstate[row * 64 + n];
            hf = first ? 0.0f : hstate[row * 64 + n];
            ((unsigned short*)hbuf[0])[n] = f2bf(hf);
            h2f[0][n] = hf;
        }
        __syncthreads();

        const float* px = xg + (size_t)row * 256 + n;
        float xc = px[0];
        float xn = (Tc > 1) ? px[(size_t)BB * 256] : 0.0f;

        int cur = 0;
        for (int t = 0; t < Tc; ++t) {
#pragma unroll
            for (int j = 0; j < 8; ++j)
                asm volatile("" : "+v"(w[j].x), "+v"(w[j].y), "+v"(w[j].z), "+v"(w[j].w));

            float a = xc;
            xc = xn;
            if (t + 2 < Tc) xn = px[(size_t)(t + 2) * BB * 256];

            const uint4* hb = (const uint4*)hbuf[cur];
#pragma unroll
            for (int j = 0; j < 8; ++j) {
                uint4 hv = hb[j];
                DOT2BF(a, w[j].x, hv.x); DOT2BF(a, w[j].y, hv.y);
                DOT2BF(a, w[j].z, hv.z); DOT2BF(a, w[j].w, hv.w);
            }
            g_lds[n] = a;
            __syncthreads();

            if (n < 64) {
                float i_ = sigm(g_lds[n]);
                float f_ = sigm(g_lds[n + 64]);
                float g_ = tanh_(g_lds[n + 128]);
                float o_ = sigm(g_lds[n + 192]);
                c  = fmaf(f_, c, i_ * g_);
                hf = o_ * tanh_(c);
                ((unsigned short*)hbuf[cur ^ 1])[n] = f2bf(hf);
                h2f[cur ^ 1][n] = hf;
            }
            cur ^= 1;
            __syncthreads();
        }
        if (n < 64) {
            cstate[row * 64 + n] = c;
            hstate[row * 64 + n] = hf;
        }
    } else {
        // ================= wave 4: layer 3 (H=1) =================
        const int lane = tid - 256;      // 0..63
        const int g    = lane >> 4;      // gate 0..3
        const int i    = lane & 15;      // element group 0..15

        float4 w3 = *(const float4*)(Wx3 + g * 64 + 4 * i);
        float b3[4], wh3[4];
#pragma unroll
        for (int k = 0; k < 4; ++k) { b3[k] = bih3[k] + bhh3[k]; wh3[k] = Wh3[k]; }
        float h3 = first ? 0.0f : st3h[row];
        float c3 = first ? 0.0f : st3c[row];

        __syncthreads();   // matches scan-side init barrier

        int cur = 0;
        for (int t = 0; t < Tc; ++t) {
            if (t >= 1) {
                float4 hv = *(const float4*)(&h2f[cur][4 * i]);
                float p = hv.x * w3.x;
                p = fmaf(hv.y, w3.y, p);
                p = fmaf(hv.z, w3.z, p);
                p = fmaf(hv.w, w3.w, p);
                p += __shfl_xor(p, 1);
                p += __shfl_xor(p, 2);
                p += __shfl_xor(p, 4);
                p += __shfl_xor(p, 8);
                float s0 = readlane_f(p, 0);
                float s1 = readlane_f(p, 16);
                float s2 = readlane_f(p, 32);
                float s3 = readlane_f(p, 48);
                float gi  = fmaf(h3, wh3[0], s0 + b3[0]);
                float gf  = fmaf(h3, wh3[1], s1 + b3[1]);
                float gg_ = fmaf(h3, wh3[2], s2 + b3[2]);
                float go  = fmaf(h3, wh3[3], s3 + b3[3]);
                float i_ = sigm(gi);
                float f_ = sigm(gf);
                float g_ = tanh_(gg_);
                float o_ = sigm(go);
                c3 = fmaf(f_, c3, i_ * g_);
                h3 = o_ * tanh_(c3);
                if (lane == 0)
                    out[(size_t)(tbase + t - 1) * BB + row] = h3;
            }
            __syncthreads();   // barrier 1
            __syncthreads();   // barrier 2
            cur ^= 1;
        }
        // tail: out[tbase+Tc-1] from h2f[cur] (last step's h2)
        {
            float4 hv = *(const float4*)(&h2f[cur][4 * i]);
            float p = hv.x * w3.x;
            p = fmaf(hv.y, w3.y, p);
            p = fmaf(hv.z, w3.z, p);
            p = fmaf(hv.w, w3.w, p);
            p += __shfl_xor(p, 1);
            p += __shfl_xor(p, 2);
            p += __shfl_xor(p, 4);
            p += __shfl_xor(p, 8);
            float s0 = readlane_f(p, 0);
            float s1 = readlane_f(p, 16);
            float s2 = readlane_f(p, 32);
            float s3 = readlane_f(p, 48);
            float gi  = fmaf(h3, wh3[0], s0 + b3[0]);
            float gf  = fmaf(h3, wh3[1], s1 + b3[1]);
            float gg_ = fmaf(h3, wh3[2], s2 + b3[2]);
            float go  = fmaf(h3, wh3[3], s3 + b3[3]);
            float i_ = sigm(gi);
            float f_ = sigm(gf);
            float g_ = tanh_(gg_);
            float o_ = sigm(go);
            c3 = fmaf(f_, c3, i_ * g_);
            h3 = o_ * tanh_(c3);
            if (lane == 0) {
                out[(size_t)(tbase + Tc - 1) * BB + row] = h3;
                st3h[row] = h3;
                st3c[row] = c3;
            }
        }
    }
}

// ---------------------------------------------------------------------------
extern "C" void kernel_launch(void* const* d_in, const int* in_sizes, int n_in,
                              void* d_out, int out_size, void* d_ws, size_t ws_size,
                              hipStream_t stream) {
    const float* x    = (const float*)d_in[0];
    const float* Wih1 = (const float*)d_in[1];
    const float* Whh1 = (const float*)d_in[2];
    const float* bih1 = (const float*)d_in[3];
    const float* bhh1 = (const float*)d_in[4];
    const float* Wih2 = (const float*)d_in[5];
    const float* Whh2 = (const float*)d_in[6];
    const float* bih2 = (const float*)d_in[7];
    const float* bhh2 = (const float*)d_in[8];
    const float* Wih3 = (const float*)d_in[9];
    const float* Whh3 = (const float*)d_in[10];
    const float* bih3 = (const float*)d_in[11];
    const float* bhh3 = (const float*)d_in[12];
    float* out = (float*)d_out;

    char* ws = (char*)d_ws;
    // Workspace ~202 MB. xg2 aliases the xg1 region (phases sequential).
    float*          xg1   = (float*)(ws + 0);                   // [256,B,512] f32 = 134,217,728
    float*          xg2   = (float*)(ws + 0);                   // [256,B,256] f32 (alias, P2 only)
    __hip_bfloat16* xb    = (__hip_bfloat16*)(ws + 134217728);  // 33,554,432
    __hip_bfloat16* h1b   = (__hip_bfloat16*)(ws + 167772160);  // 33,554,432
    __hip_bfloat16* wb1   = (__hip_bfloat16*)(ws + 201326592);  //   131,072
    __hip_bfloat16* whb1  = (__hip_bfloat16*)(ws + 201457664);  //   131,072
    __hip_bfloat16* wb2   = (__hip_bfloat16*)(ws + 201588736);  //    65,536
    __hip_bfloat16* whb2  = (__hip_bfloat16*)(ws + 201654272);  //    32,768
    float*          bias1 = (float*)(ws + 201687040);           //     2,048
    float*          bias2 = (float*)(ws + 201689088);           //     1,024
    float*          st1h  = (float*)(ws + 201690112);           //   131,072
    float*          st1c  = (float*)(ws + 201821184);           //   131,072
    float*          st2h  = (float*)(ws + 201952256);           //    65,536
    float*          st2c  = (float*)(ws + 202017792);           //    65,536
    float*          st3h  = (float*)(ws + 202083328);           //     1,024
    float*          st3c  = (float*)(ws + 202084352);           //     1,024

    // ---- P0: conversions / bias prep (2 launches) ----
    cvt_pad_x<<<4096, 256, 0, stream>>>(x, xb);
    prep_small<<<708, 256, 0, stream>>>(
        Wih1, Whh1, Wih2, Whh2, bih1, bhh1, bih2, bhh2,
        wb1, whb1, wb2, whb2, bias1, bias2);

    // ---- P1: Layer 1 (2 chunks of 256 steps) ----
    for (int c0 = 0; c0 < NCH; ++c0) {
        gemm_mfma<<<dim3(CH * BB / 128, 512 / 128), 256, 0, stream>>>(
            xb + (size_t)c0 * CH * BB * 128, wb1, bias1, xg1, 512);
        lstm_scan1<<<BB, 512, 0, stream>>>(
            xg1, (const unsigned int*)whb1,
            h1b + (size_t)c0 * CH * BB * 128, st1h, st1c, CH, c0 == 0);
    }
    // ---- P2: Layers 2+3 (2 chunks; L3 fused on wave 4) ----
    for (int c0 = 0; c0 < NCH; ++c0) {
        gemm_mfma<<<dim3(CH * BB / 128, 256 / 128), 256, 0, stream>>>(
            h1b + (size_t)c0 * CH * BB * 128, wb2, bias2, xg2, 256);
        lstm_scan23<<<BB, 320, 0, stream>>>(
            xg2, (const unsigned int*)whb2, st2h, st2c,
            Wih3, Whh3, bih3, bhh3, st3h, st3c, out,
            CH, c0 == 0, c0 * CH);
    }
}